// Round 1
// baseline (417.932 us; speedup 1.0000x reference)
//
#include <hip/hip_runtime.h>
#include <hip/hip_bf16.h>
#include <math.h>

#define B_SZ   1024
#define CDIM   768
#define POOL   100
#define LP     8
#define COSEPS 1e-6f

// ---------------- Kernel 1: prep (softmax rows of A, W1/W2/k_norm) ----------
__global__ void prep_kernel(const float* __restrict__ A, const float* __restrict__ K,
                            float* __restrict__ W1, float* __restrict__ W2,
                            float* __restrict__ knorm) {
    const int k = blockIdx.x;       // 0..99
    const int t = threadIdx.x;      // 0..255
    __shared__ float red[256];

    const float* Ar = A + (size_t)k * CDIM;
    const float* Kr = K + (size_t)k * CDIM;

    // row max of A
    float m = -INFINITY;
    for (int d = t; d < CDIM; d += 256) m = fmaxf(m, Ar[d]);
    red[t] = m; __syncthreads();
    for (int s = 128; s > 0; s >>= 1) { if (t < s) red[t] = fmaxf(red[t], red[t + s]); __syncthreads(); }
    m = red[0]; __syncthreads();

    // sum of exp
    float sum = 0.f;
    for (int d = t; d < CDIM; d += 256) sum += expf(Ar[d] - m);
    red[t] = sum; __syncthreads();
    for (int s = 128; s > 0; s >>= 1) { if (t < s) red[t] += red[t + s]; __syncthreads(); }
    sum = red[0]; __syncthreads();
    const float inv = 1.0f / sum;

    // K row squared-norm
    float ksq = 0.f;
    for (int d = t; d < CDIM; d += 256) { float kv = Kr[d]; ksq += kv * kv; }
    red[t] = ksq; __syncthreads();
    for (int s = 128; s > 0; s >>= 1) { if (t < s) red[t] += red[t + s]; __syncthreads(); }
    if (t == 0) knorm[k] = fmaxf(sqrtf(red[0]), COSEPS);

    // W1 = A_sm * K, W2 = A_sm^2
    for (int d = t; d < CDIM; d += 256) {
        float a_sm = expf(Ar[d] - m) * inv;
        W1[(size_t)k * CDIM + d] = a_sm * Kr[d];
        W2[(size_t)k * CDIM + d] = a_sm * a_sm;
    }
}

// ---------------- Kernel 2: aq[b][k] -----------------------------------------
__global__ void aq_kernel(const float* __restrict__ xq,
                          const float* __restrict__ W1, const float* __restrict__ W2,
                          const float* __restrict__ knorm, float* __restrict__ aq) {
    const int b = blockIdx.x;     // 0..1023
    const int t = threadIdx.x;    // 0..255 (4 waves of 64)
    __shared__ float xs[CDIM];
    __shared__ float x2s[CDIM];

    for (int d = t; d < CDIM; d += 256) {
        float v = xq[(size_t)b * CDIM + d];
        xs[d] = v; x2s[d] = v * v;
    }
    __syncthreads();

    const int wave = t >> 6, lane = t & 63;
    for (int k = wave; k < POOL; k += 4) {
        const float* w1 = W1 + (size_t)k * CDIM;
        const float* w2 = W2 + (size_t)k * CDIM;
        float s1 = 0.f, s2 = 0.f;
        #pragma unroll
        for (int i = 0; i < CDIM / 64; ++i) {
            int d = lane + i * 64;
            s1 += xs[d] * w1[d];
            s2 += x2s[d] * w2[d];
        }
        // wave-64 reduction
        for (int off = 32; off > 0; off >>= 1) {
            s1 += __shfl_down(s1, off);
            s2 += __shfl_down(s2, off);
        }
        if (lane == 0) {
            float an = fmaxf(sqrtf(s2), COSEPS);
            float v  = s1 / (an * knorm[k]);
            aq[(size_t)b * POOL + k] = (v + 1.0f) * 0.5f;
        }
    }
}

// ---------------- Kernel 3: P_ = aq x p, write Ek/Ev --------------------------
// grid = 8 (l) * 128 (groups of 8 b), block = 256
__global__ void p_kernel(const float* __restrict__ aq, const float* __restrict__ p,
                         float* __restrict__ out) {
    const int l  = blockIdx.x & 7;
    const int bg = blockIdx.x >> 3;   // 0..127
    const int t  = threadIdx.x;
    __shared__ float a_s[POOL * 8];   // [k][bb]

    for (int i = t; i < POOL * 8; i += 256) {
        int bb = i & 7, k = i >> 3;
        a_s[i] = aq[(size_t)(bg * 8 + bb) * POOL + k];
    }
    __syncthreads();

    const float* pl = p + (size_t)l * POOL * CDIM + t;
    float acc[8][3];
    #pragma unroll
    for (int bb = 0; bb < 8; ++bb)
        #pragma unroll
        for (int j = 0; j < 3; ++j) acc[bb][j] = 0.f;

    for (int k = 0; k < POOL; ++k) {
        float p0 = pl[(size_t)k * CDIM];
        float p1 = pl[(size_t)k * CDIM + 256];
        float p2 = pl[(size_t)k * CDIM + 512];
        #pragma unroll
        for (int bb = 0; bb < 8; ++bb) {
            float a = a_s[k * 8 + bb];
            acc[bb][0] += a * p0;
            acc[bb][1] += a * p1;
            acc[bb][2] += a * p2;
        }
    }

    const size_t EK_SZ = (size_t)B_SZ * (LP / 2) * CDIM;   // 1024*4*768
    #pragma unroll
    for (int bb = 0; bb < 8; ++bb) {
        int b = bg * 8 + bb;
        float* dst = (l < 4)
            ? out + (size_t)b * (4 * CDIM) + (size_t)l * CDIM
            : out + EK_SZ + (size_t)b * (4 * CDIM) + (size_t)(l - 4) * CDIM;
        dst[t]       = acc[bb][0];
        dst[t + 256] = acc[bb][1];
        dst[t + 512] = acc[bb][2];
    }
}

extern "C" void kernel_launch(void* const* d_in, const int* in_sizes, int n_in,
                              void* d_out, int out_size, void* d_ws, size_t ws_size,
                              hipStream_t stream) {
    const float* x_querry = (const float*)d_in[0];
    const float* x_block  = (const float*)d_in[1];
    const float* K        = (const float*)d_in[2];
    const float* A        = (const float*)d_in[3];
    const float* p        = (const float*)d_in[4];
    float* out = (float*)d_out;

    // workspace layout (floats)
    float* W1    = (float*)d_ws;                 // 100*768
    float* W2    = W1 + POOL * CDIM;             // 100*768
    float* knorm = W2 + POOL * CDIM;             // 100 (pad 128)
    float* aq    = knorm + 128;                  // 1024*100

    prep_kernel<<<POOL, 256, 0, stream>>>(A, K, W1, W2, knorm);
    aq_kernel<<<B_SZ, 256, 0, stream>>>(x_querry, W1, W2, knorm, aq);
    p_kernel<<<8 * (B_SZ / 8), 256, 0, stream>>>(aq, p, out);

    // x_block pass-through: out offset = 2 * (1024*4*768)
    const size_t EK_SZ = (size_t)B_SZ * (LP / 2) * CDIM;
    const size_t XB_BYTES = (size_t)in_sizes[1] * sizeof(float);
    hipMemcpyAsync(out + 2 * EK_SZ, x_block, XB_BYTES, hipMemcpyDeviceToDevice, stream);
}